// Round 5
// baseline (352.642 us; speedup 1.0000x reference)
//
#include <hip/hip_runtime.h>

constexpr int B_ = 4, N_ = 2048, I_ = 256, O_ = 128, H_ = 8;
constexpr float LOG2E = 1.4426950408889634f;
constexpr int LDP = 132;          // padded LDS row (floats): 16B-aligned, +4 bank shift/row
constexpr int GEMM_BLOCKS = 512;  // (N/128) * (B*H) = 16 * 32

#define EXP2(x) __builtin_amdgcn_exp2f(x)

// ---------------------------------------------------------------------------
// Kernel 1 (grid-union):
//   blocks [0,512):    Wh GEMM (128n x 128o tile, 8x8/thread) + u/v epilogue
//   blocks [512,2560): adj -> packed nibble masks (BW-bound, overlaps GEMM)
// mask layout: nb[row*512 + lane*8 + kk] bit j <-> column c = (kk*64+lane)*4+j
// u,v are PRE-SCALED by log2(e).
// ---------------------------------------------------------------------------
__global__ __launch_bounds__(256) void gemm_mask(
    const float* __restrict__ hin, const float* __restrict__ cw,
    const float* __restrict__ cb, const float* __restrict__ a,
    const float* __restrict__ wb1, const float* __restrict__ wb2,
    const float* __restrict__ adj,
    float* __restrict__ Wh, float* __restrict__ u, float* __restrict__ v,
    unsigned char* __restrict__ nb)
{
  __shared__ float hsT[32 * LDP];
  __shared__ float wT[32 * LDP];
  const int tid = threadIdx.x;

  if (blockIdx.x >= GEMM_BLOCKS) {
    // ---- mask part: 4 rows/block, one wave per row, packed u64 store ----
    const int row = (blockIdx.x - GEMM_BLOCKS) * 4 + (tid >> 6);  // b*N + r
    const int ml  = tid & 63;
    const float* arow = &adj[(size_t)row * N_];
    unsigned long long acc64 = 0ull;
    #pragma unroll
    for (int it = 0; it < 8; ++it) {
      int g = it * 64 + ml;
      float4 a4 = *(const float4*)&arow[g * 4];
      unsigned long long nib =
          (unsigned long long)(a4.x >= 0.5f)
        | ((unsigned long long)(a4.y >= 0.5f) << 1)
        | ((unsigned long long)(a4.z >= 0.5f) << 2)
        | ((unsigned long long)(a4.w >= 0.5f) << 3);
      acc64 |= nib << (8 * it);
    }
    *(unsigned long long*)&nb[(size_t)row * 512 + ml * 8] = acc64;
    return;
  }

  // ---- GEMM part: tile 128n x 128o per block (one (b,h)) ----
  const int bid = blockIdx.x;
  const int n0  = (bid & 15) * 128;
  const int by  = bid >> 4;
  const int b   = by >> 3;
  const int hh  = by & 7;
  const int tn  = tid >> 4;   // 0..15
  const int to  = tid & 15;   // 0..15

  float acc[2][4][8];
  #pragma unroll
  for (int g = 0; g < 2; ++g)
    #pragma unroll
    for (int j = 0; j < 4; ++j)
      #pragma unroll
      for (int c = 0; c < 8; ++c) acc[g][j][c] = 0.f;

  for (int i0 = 0; i0 < I_; i0 += 32) {
    __syncthreads();
    #pragma unroll
    for (int kk = 0; kk < 4; ++kk) {
      int f4 = tid + kk * 256;
      int n  = f4 >> 3;            // 0..127 (also used as o for w tile)
      int i4 = (f4 & 7) * 4;
      float4 hv = *(const float4*)&hin[((size_t)(b * N_ + n0 + n)) * I_ + i0 + i4];
      hsT[(i4 + 0) * LDP + n] = hv.x; hsT[(i4 + 1) * LDP + n] = hv.y;
      hsT[(i4 + 2) * LDP + n] = hv.z; hsT[(i4 + 3) * LDP + n] = hv.w;
      float4 wv = *(const float4*)&cw[((size_t)(hh * O_ + n)) * I_ + i0 + i4];
      wT[(i4 + 0) * LDP + n] = wv.x; wT[(i4 + 1) * LDP + n] = wv.y;
      wT[(i4 + 2) * LDP + n] = wv.z; wT[(i4 + 3) * LDP + n] = wv.w;
    }
    __syncthreads();
    #pragma unroll 8
    for (int k = 0; k < 32; ++k) {
      const float* hr = &hsT[k * LDP];
      const float* wr = &wT[k * LDP];
      float4 av0 = *(const float4*)&hr[tn * 4];
      float4 av1 = *(const float4*)&hr[64 + tn * 4];
      float4 bv0 = *(const float4*)&wr[to * 4];
      float4 bv1 = *(const float4*)&wr[64 + to * 4];
      float aj;
      #define FMA_ROW(G, J, COMP)                                         \
        aj = COMP;                                                        \
        acc[G][J][0] = fmaf(aj, bv0.x, acc[G][J][0]);                     \
        acc[G][J][1] = fmaf(aj, bv0.y, acc[G][J][1]);                     \
        acc[G][J][2] = fmaf(aj, bv0.z, acc[G][J][2]);                     \
        acc[G][J][3] = fmaf(aj, bv0.w, acc[G][J][3]);                     \
        acc[G][J][4] = fmaf(aj, bv1.x, acc[G][J][4]);                     \
        acc[G][J][5] = fmaf(aj, bv1.y, acc[G][J][5]);                     \
        acc[G][J][6] = fmaf(aj, bv1.z, acc[G][J][6]);                     \
        acc[G][J][7] = fmaf(aj, bv1.w, acc[G][J][7]);
      FMA_ROW(0, 0, av0.x) FMA_ROW(0, 1, av0.y) FMA_ROW(0, 2, av0.z) FMA_ROW(0, 3, av0.w)
      FMA_ROW(1, 0, av1.x) FMA_ROW(1, 1, av1.y) FMA_ROW(1, 2, av1.z) FMA_ROW(1, 3, av1.w)
      #undef FMA_ROW
    }
  }

  float4 cb0 = *(const float4*)&cb[hh * O_ + to * 4];
  float4 cb1 = *(const float4*)&cb[hh * O_ + to * 4 + 64];
  const float* ah = &a[hh * 2 * O_];
  float4 a1l = *(const float4*)&ah[to * 4];
  float4 a1h = *(const float4*)&ah[64 + to * 4];
  float4 a2l = *(const float4*)&ah[128 + to * 4];
  float4 a2h = *(const float4*)&ah[192 + to * 4];

  #pragma unroll
  for (int g = 0; g < 2; ++g) {
    #pragma unroll
    for (int j = 0; j < 4; ++j) {
      float* A = acc[g][j];
      A[0] += cb0.x; A[1] += cb0.y; A[2] += cb0.z; A[3] += cb0.w;
      A[4] += cb1.x; A[5] += cb1.y; A[6] += cb1.z; A[7] += cb1.w;
      int n = n0 + g * 64 + tn * 4 + j;
      size_t base = (((size_t)(b * N_ + n)) * H_ + hh) * O_;
      *(float4*)&Wh[base + to * 4]      = make_float4(A[0], A[1], A[2], A[3]);
      *(float4*)&Wh[base + to * 4 + 64] = make_float4(A[4], A[5], A[6], A[7]);

      float pu = A[0]*a1l.x + A[1]*a1l.y + A[2]*a1l.z + A[3]*a1l.w
               + A[4]*a1h.x + A[5]*a1h.y + A[6]*a1h.z + A[7]*a1h.w;
      float pv = A[0]*a2l.x + A[1]*a2l.y + A[2]*a2l.z + A[3]*a2l.w
               + A[4]*a2h.x + A[5]*a2h.y + A[6]*a2h.z + A[7]*a2h.w;
      #pragma unroll
      for (int off = 8; off; off >>= 1) {
        pu += __shfl_xor(pu, off);
        pv += __shfl_xor(pv, off);
      }
      if (to == 0) {
        int idx = (b * H_ + hh) * N_ + n;
        u[idx] = (pu + wb1[hh * N_ + n] + wb2[hh * N_ + n]) * LOG2E;
        v[idx] = pv * LOG2E;
      }
    }
  }
}

// ---------------------------------------------------------------------------
// Kernel 2: single-pass log2-domain softmax denominator + fused
// elu(diag*Wh + attb) epilogue. All loads hoisted to the top for MLP.
// Block = (r, h), 4 waves = 4 batches. No LDS, no barriers.
// ---------------------------------------------------------------------------
__global__ __launch_bounds__(256) void attn_fused(
    const unsigned char* __restrict__ nb, const float* __restrict__ abias,
    const float* __restrict__ u, const float* __restrict__ v,
    const float* __restrict__ Wh, const float* __restrict__ attb,
    float* __restrict__ out)
{
  const int r    = blockIdx.x;
  const int hh   = blockIdx.y;
  const int lane = threadIdx.x & 63;
  const int b    = threadIdx.x >> 6;
  const int bh   = b * H_ + hh;

  const float* vrow  = &v[(size_t)bh * N_];
  const float* abrow = &abias[((size_t)(hh * N_ + r)) * N_];
  const unsigned char* nrow = &nb[(size_t)(b * N_ + r) * 512];

  // ---- issue everything up front ----
  uint2 mk = *(const uint2*)&nrow[lane * 8];
  float4 vv[8], aa[8];
  #pragma unroll
  for (int kk = 0; kk < 8; ++kk) {
    int c4 = kk * 256 + lane * 4;
    vv[kk] = *(const float4*)&vrow[c4];
    aa[kk] = *(const float4*)&abrow[c4];
  }
  const size_t obase = (((size_t)(b * N_ + r)) * H_ + hh) * O_;
  const float* atr = &attb[((size_t)(hh * N_ + r)) * O_];
  float wh0 = Wh[obase + lane], wh1 = Wh[obase + lane + 64];
  float at0 = atr[lane],        at1 = atr[lane + 64];
  float uval = u[bh * N_ + r];
  float vdiag = vrow[r];

  // ---- single-pass exp2 sum, 4 independent accumulators ----
  float ss0 = 0.f, ss1 = 0.f, ss2 = 0.f, ss3 = 0.f;
  #pragma unroll
  for (int kk = 0; kk < 8; ++kk) {
    unsigned int nib =
        (kk < 4 ? (mk.x >> (kk * 8)) : (mk.y >> ((kk - 4) * 8))) & 0xffu;
    float4 v4 = vv[kk], a4 = aa[kk];
    float pre, lr, e;
    #define COL(J, VC, AC, SS)                                            \
      pre = uval + VC;                                                    \
      lr  = fmaxf(pre, 0.2f * pre);                                       \
      e   = EXP2(fmaf(AC, LOG2E, lr));                                    \
      SS += (nib & (1u << J)) ? e : 0.f;
    COL(0, v4.x, a4.x, ss0) COL(1, v4.y, a4.y, ss1)
    COL(2, v4.z, a4.z, ss2) COL(3, v4.w, a4.w, ss3)
    #undef COL
  }
  float ss = (ss0 + ss1) + (ss2 + ss3);
  #pragma unroll
  for (int off = 32; off; off >>= 1) ss += __shfl_xor(ss, off);

  // ---- diagonal (uniform across lanes) ----
  int gd = r >> 2;
  unsigned int nibd = nrow[(gd & 63) * 8 + (gd >> 6)];
  float prd = uval + vdiag;
  float lrd = fmaxf(prd, 0.2f * prd);
  float numd = EXP2(fmaf(abrow[r], LOG2E, lrd));
  float diag = ((nibd >> (r & 3)) & 1u) ? numd / ss : 0.f;

  // ---- fused elu epilogue ----
  float x0 = fmaf(diag, wh0, at0);
  float x1 = fmaf(diag, wh1, at1);
  out[obase + lane]      = x0 > 0.f ? x0 : __expf(x0) - 1.f;
  out[obase + lane + 64] = x1 > 0.f ? x1 : __expf(x1) - 1.f;
}

extern "C" void kernel_launch(void* const* d_in, const int* in_sizes, int n_in,
                              void* d_out, int out_size, void* d_ws, size_t ws_size,
                              hipStream_t stream) {
  const float* hin   = (const float*)d_in[0];
  const float* adj   = (const float*)d_in[1];
  const float* cw    = (const float*)d_in[2];
  const float* cb    = (const float*)d_in[3];
  const float* a     = (const float*)d_in[4];
  const float* wb1   = (const float*)d_in[5];
  const float* wb2   = (const float*)d_in[6];
  const float* abias = (const float*)d_in[7];
  const float* attb  = (const float*)d_in[8];
  float* out = (float*)d_out;

  float* u = (float*)d_ws;                                        // B*H*N f32
  float* v = u + (size_t)B_ * H_ * N_;                            // B*H*N f32
  unsigned char* nb = (unsigned char*)(v + (size_t)B_ * H_ * N_); // B*N*512 u8
  float* whws = (float*)(nb + (size_t)B_ * N_ * 512);

  size_t needBytes = ((size_t)B_ * H_ * N_ * 2) * 4 + (size_t)B_ * N_ * 512
                   + (size_t)B_ * N_ * H_ * O_ * 4;
  // Prefer workspace for Wh; fall back to d_out (in-place safe: attn_fused
  // reads Wh[idx] then writes out[idx] at the identical address).
  float* Wh = (ws_size >= needBytes) ? whws : out;

  gemm_mask<<<dim3(GEMM_BLOCKS + B_ * N_ / 4), 256, 0, stream>>>(
      hin, cw, cb, a, wb1, wb2, adj, Wh, u, v, nb);
  attn_fused<<<dim3(N_, H_), 256, 0, stream>>>(nb, abias, u, v, Wh, attb, out);
}

// Round 6
// 311.842 us; speedup vs baseline: 1.1308x; 1.1308x over previous
//
#include <hip/hip_runtime.h>

constexpr int B_ = 4, N_ = 2048, I_ = 256, O_ = 128, H_ = 8;
constexpr float LOG2E = 1.4426950408889634f;
constexpr int GEMM_BLOCKS = 512;   // 16 n-tiles x 32 (b,h)

using bf16x8 = __attribute__((ext_vector_type(8))) short;
using f32x4  = __attribute__((ext_vector_type(4))) float;

#define EXP2(x) __builtin_amdgcn_exp2f(x)

__device__ __forceinline__ unsigned pk_bf16(float lo, float hi) {
  unsigned r;
  asm("v_cvt_pk_bf16_f32 %0, %1, %2" : "=v"(r) : "v"(lo), "v"(hi));
  return r;
}

// ---------------------------------------------------------------------------
// Kernel 1 (grid-union):
//   blocks [0,512):    Wh = h x cw^T via bf16 MFMA (128n x 128o tile, 4 waves
//                      of 64x64) + f32 u/v epilogue.  u,v pre-scaled by log2e.
//   blocks [512,2560): adj -> packed nibble masks (BW-bound, overlaps GEMM)
// mask layout: nb[row*512 + lane*8 + kk] bit j <-> column c = (kk*64+lane)*4+j
// ---------------------------------------------------------------------------
__global__ __launch_bounds__(256) void gemm_mask(
    const float* __restrict__ hin, const float* __restrict__ cw,
    const float* __restrict__ cb, const float* __restrict__ a,
    const float* __restrict__ wb1, const float* __restrict__ wb2,
    const float* __restrict__ adj,
    float* __restrict__ Wh, float* __restrict__ u, float* __restrict__ v,
    unsigned char* __restrict__ nb)
{
  // bf16 tiles, rows padded to 40 shorts (80 B) -> 2-way-max bank aliasing
  __shared__ __align__(16) short tA[128 * 40];
  __shared__ __align__(16) short tB[128 * 40];
  __shared__ float up[2][128], vp[2][128];
  const int tid = threadIdx.x;

  if (blockIdx.x >= GEMM_BLOCKS) {
    // ---- mask part: 4 rows/block, one wave per row, packed u64 store ----
    const int row = (blockIdx.x - GEMM_BLOCKS) * 4 + (tid >> 6);  // b*N + r
    const int ml  = tid & 63;
    const float* arow = &adj[(size_t)row * N_];
    unsigned long long acc64 = 0ull;
    #pragma unroll
    for (int it = 0; it < 8; ++it) {
      int g = it * 64 + ml;
      float4 a4 = *(const float4*)&arow[g * 4];
      unsigned long long nib =
          (unsigned long long)(a4.x >= 0.5f)
        | ((unsigned long long)(a4.y >= 0.5f) << 1)
        | ((unsigned long long)(a4.z >= 0.5f) << 2)
        | ((unsigned long long)(a4.w >= 0.5f) << 3);
      acc64 |= nib << (8 * it);
    }
    *(unsigned long long*)&nb[(size_t)row * 512 + ml * 8] = acc64;
    return;
  }

  // ---- MFMA GEMM part ----
  const int bid = blockIdx.x;
  const int n0  = (bid & 15) * 128;
  const int by  = bid >> 4;
  const int b   = by >> 3;
  const int hh  = by & 7;
  const int lane = tid & 63, wid = tid >> 6;
  const int wm = wid >> 1, wn = wid & 1;   // wave tile: rows wm*64, cols wn*64
  const int lr = lane & 15;                // frag row (A) / col (B,D)
  const int lg = lane >> 4;                // k-group; D row group

  f32x4 acc[4][4];
  #pragma unroll
  for (int i = 0; i < 4; ++i)
    #pragma unroll
    for (int j = 0; j < 4; ++j) acc[i][j] = (f32x4){0.f, 0.f, 0.f, 0.f};

  // staging map: thread t -> row t>>1 (0..127), k-half (t&1)*16 of 32-k step
  const int srow = tid >> 1;
  const int skh  = (tid & 1) << 4;
  const float* gA = &hin[((size_t)(b * N_ + n0 + srow)) * I_ + skh];
  const float* gB = &cw[((size_t)(hh * O_ + srow)) * I_ + skh];
  uint4* wA = (uint4*)&tA[srow * 40 + skh];
  uint4* wB = (uint4*)&tB[srow * 40 + skh];

  float4 ra[4], rb[4];
  #pragma unroll
  for (int q = 0; q < 4; ++q) {
    ra[q] = *(const float4*)&gA[q * 4];
    rb[q] = *(const float4*)&gB[q * 4];
  }

  for (int step = 0; step < 8; ++step) {
    // convert staged regs -> bf16 LDS (prev-step reads fenced by loop barrier)
    wA[0] = make_uint4(pk_bf16(ra[0].x, ra[0].y), pk_bf16(ra[0].z, ra[0].w),
                       pk_bf16(ra[1].x, ra[1].y), pk_bf16(ra[1].z, ra[1].w));
    wA[1] = make_uint4(pk_bf16(ra[2].x, ra[2].y), pk_bf16(ra[2].z, ra[2].w),
                       pk_bf16(ra[3].x, ra[3].y), pk_bf16(ra[3].z, ra[3].w));
    wB[0] = make_uint4(pk_bf16(rb[0].x, rb[0].y), pk_bf16(rb[0].z, rb[0].w),
                       pk_bf16(rb[1].x, rb[1].y), pk_bf16(rb[1].z, rb[1].w));
    wB[1] = make_uint4(pk_bf16(rb[2].x, rb[2].y), pk_bf16(rb[2].z, rb[2].w),
                       pk_bf16(rb[3].x, rb[3].y), pk_bf16(rb[3].z, rb[3].w));
    if (step < 7) {  // prefetch next k-step; latency hides across mfma phase
      int i0 = (step + 1) * 32;
      #pragma unroll
      for (int q = 0; q < 4; ++q) {
        ra[q] = *(const float4*)&gA[i0 + q * 4];
        rb[q] = *(const float4*)&gB[i0 + q * 4];
      }
    }
    __syncthreads();
    bf16x8 af[4], bf[4];
    #pragma unroll
    for (int im = 0; im < 4; ++im)
      af[im] = *(const bf16x8*)&tA[(wm * 64 + im * 16 + lr) * 40 + lg * 8];
    #pragma unroll
    for (int in = 0; in < 4; ++in)
      bf[in] = *(const bf16x8*)&tB[(wn * 64 + in * 16 + lr) * 40 + lg * 8];
    #pragma unroll
    for (int im = 0; im < 4; ++im)
      #pragma unroll
      for (int in = 0; in < 4; ++in)
        acc[im][in] = __builtin_amdgcn_mfma_f32_16x16x32_bf16(
            af[im], bf[in], acc[im][in], 0, 0, 0);
    __syncthreads();
  }

  // ---- epilogue: +conv_b, store Wh, u/v partial dot + 16-lane reduce ----
  const float* ah = &a[hh * 2 * O_];
  float a1v[4], a2v[4], cbv[4];
  #pragma unroll
  for (int in = 0; in < 4; ++in) {
    int o = wn * 64 + in * 16 + lr;
    a1v[in] = ah[o];
    a2v[in] = ah[O_ + o];
    cbv[in] = cb[hh * O_ + o];
  }
  #pragma unroll
  for (int im = 0; im < 4; ++im) {
    float su0 = 0.f, su1 = 0.f, su2 = 0.f, su3 = 0.f;
    float sv0 = 0.f, sv1 = 0.f, sv2 = 0.f, sv3 = 0.f;
    #pragma unroll
    for (int in = 0; in < 4; ++in) {
      int o = wn * 64 + in * 16 + lr;
      #pragma unroll
      for (int reg = 0; reg < 4; ++reg) {
        float val = acc[im][in][reg] + cbv[in];
        int n = n0 + wm * 64 + im * 16 + lg * 4 + reg;
        Wh[(((size_t)(b * N_ + n)) * H_ + hh) * O_ + o] = val;
        float s1 = fmaf(val, a1v[in], 0.f);
        float s2 = fmaf(val, a2v[in], 0.f);
        if (reg == 0) { su0 += s1; sv0 += s2; }
        else if (reg == 1) { su1 += s1; sv1 += s2; }
        else if (reg == 2) { su2 += s1; sv2 += s2; }
        else { su3 += s1; sv3 += s2; }
      }
    }
    float su[4] = {su0, su1, su2, su3};
    float sv[4] = {sv0, sv1, sv2, sv3};
    #pragma unroll
    for (int reg = 0; reg < 4; ++reg) {
      float x = su[reg], y = sv[reg];
      #pragma unroll
      for (int off = 1; off <= 8; off <<= 1) {
        x += __shfl_xor(x, off);
        y += __shfl_xor(y, off);
      }
      if (lr == 0) {
        int tr = wm * 64 + im * 16 + lg * 4 + reg;
        up[wn][tr] = x;
        vp[wn][tr] = y;
      }
    }
  }
  __syncthreads();
  if (tid < 128) {
    int n = n0 + tid;
    int idx = (b * H_ + hh) * N_ + n;
    u[idx] = (up[0][tid] + up[1][tid] + wb1[hh * N_ + n] + wb2[hh * N_ + n]) * LOG2E;
    v[idx] = (vp[0][tid] + vp[1][tid]) * LOG2E;
  }
}

// ---------------------------------------------------------------------------
// Kernel 2: single-pass log2-domain softmax denominator + fused
// elu(diag*Wh + attb) epilogue. All loads hoisted to the top for MLP.
// Block = (r, h), 4 waves = 4 batches. No LDS, no barriers.
// ---------------------------------------------------------------------------
__global__ __launch_bounds__(256) void attn_fused(
    const unsigned char* __restrict__ nb, const float* __restrict__ abias,
    const float* __restrict__ u, const float* __restrict__ v,
    const float* __restrict__ Wh, const float* __restrict__ attb,
    float* __restrict__ out)
{
  const int r    = blockIdx.x;
  const int hh   = blockIdx.y;
  const int lane = threadIdx.x & 63;
  const int b    = threadIdx.x >> 6;
  const int bh   = b * H_ + hh;

  const float* vrow  = &v[(size_t)bh * N_];
  const float* abrow = &abias[((size_t)(hh * N_ + r)) * N_];
  const unsigned char* nrow = &nb[(size_t)(b * N_ + r) * 512];

  // ---- issue everything up front ----
  uint2 mk = *(const uint2*)&nrow[lane * 8];
  float4 vv[8], aa[8];
  #pragma unroll
  for (int kk = 0; kk < 8; ++kk) {
    int c4 = kk * 256 + lane * 4;
    vv[kk] = *(const float4*)&vrow[c4];
    aa[kk] = *(const float4*)&abrow[c4];
  }
  const size_t obase = (((size_t)(b * N_ + r)) * H_ + hh) * O_;
  const float* atr = &attb[((size_t)(hh * N_ + r)) * O_];
  float wh0 = Wh[obase + lane], wh1 = Wh[obase + lane + 64];
  float at0 = atr[lane],        at1 = atr[lane + 64];
  float uval = u[bh * N_ + r];
  float vdiag = vrow[r];

  // ---- single-pass exp2 sum, 4 independent accumulators ----
  float ss0 = 0.f, ss1 = 0.f, ss2 = 0.f, ss3 = 0.f;
  #pragma unroll
  for (int kk = 0; kk < 8; ++kk) {
    unsigned int nib =
        (kk < 4 ? (mk.x >> (kk * 8)) : (mk.y >> ((kk - 4) * 8))) & 0xffu;
    float4 v4 = vv[kk], a4 = aa[kk];
    float pre, lr, e;
    #define COL(J, VC, AC, SS)                                            \
      pre = uval + VC;                                                    \
      lr  = fmaxf(pre, 0.2f * pre);                                       \
      e   = EXP2(fmaf(AC, LOG2E, lr));                                    \
      SS += (nib & (1u << J)) ? e : 0.f;
    COL(0, v4.x, a4.x, ss0) COL(1, v4.y, a4.y, ss1)
    COL(2, v4.z, a4.z, ss2) COL(3, v4.w, a4.w, ss3)
    #undef COL
  }
  float ss = (ss0 + ss1) + (ss2 + ss3);
  #pragma unroll
  for (int off = 32; off; off >>= 1) ss += __shfl_xor(ss, off);

  // ---- diagonal (uniform across lanes) ----
  int gd = r >> 2;
  unsigned int nibd = nrow[(gd & 63) * 8 + (gd >> 6)];
  float prd = uval + vdiag;
  float lrd = fmaxf(prd, 0.2f * prd);
  float numd = EXP2(fmaf(abrow[r], LOG2E, lrd));
  float diag = ((nibd >> (r & 3)) & 1u) ? numd / ss : 0.f;

  // ---- fused elu epilogue ----
  float x0 = fmaf(diag, wh0, at0);
  float x1 = fmaf(diag, wh1, at1);
  out[obase + lane]      = x0 > 0.f ? x0 : __expf(x0) - 1.f;
  out[obase + lane + 64] = x1 > 0.f ? x1 : __expf(x1) - 1.f;
}

extern "C" void kernel_launch(void* const* d_in, const int* in_sizes, int n_in,
                              void* d_out, int out_size, void* d_ws, size_t ws_size,
                              hipStream_t stream) {
  const float* hin   = (const float*)d_in[0];
  const float* adj   = (const float*)d_in[1];
  const float* cw    = (const float*)d_in[2];
  const float* cb    = (const float*)d_in[3];
  const float* a     = (const float*)d_in[4];
  const float* wb1   = (const float*)d_in[5];
  const float* wb2   = (const float*)d_in[6];
  const float* abias = (const float*)d_in[7];
  const float* attb  = (const float*)d_in[8];
  float* out = (float*)d_out;

  float* u = (float*)d_ws;                                        // B*H*N f32
  float* v = u + (size_t)B_ * H_ * N_;                            // B*H*N f32
  unsigned char* nb = (unsigned char*)(v + (size_t)B_ * H_ * N_); // B*N*512 u8
  float* whws = (float*)(nb + (size_t)B_ * N_ * 512);

  size_t needBytes = ((size_t)B_ * H_ * N_ * 2) * 4 + (size_t)B_ * N_ * 512
                   + (size_t)B_ * N_ * H_ * O_ * 4;
  // Prefer workspace for Wh; fall back to d_out (in-place safe: attn_fused
  // reads Wh[idx] then writes out[idx] at the identical address).
  float* Wh = (ws_size >= needBytes) ? whws : out;

  gemm_mask<<<dim3(GEMM_BLOCKS + B_ * N_ / 4), 256, 0, stream>>>(
      hin, cw, cb, a, wb1, wb2, adj, Wh, u, v, nb);
  attn_fused<<<dim3(N_, H_), 256, 0, stream>>>(nb, abias, u, v, Wh, attb, out);
}